// Round 7
// baseline (71.797 us; speedup 1.0000x reference)
//
#include <hip/hip_runtime.h>
#include <math.h>

typedef unsigned long long ull;

#define TT 64
#define NN 32
#define CC 128
#define DD 64

__device__ __forceinline__ float rdlane(float x, int l) {
    return __builtin_bit_cast(float,
        __builtin_amdgcn_readlane(__builtin_bit_cast(int, x), l));
}

// ---------------------------------------------------------------------------
// Kernel 1a: one wave per (n,c). lane = jeffress dim d. (round-6 verbatim)
// ---------------------------------------------------------------------------
__global__ __launch_bounds__(256) void k1a_jeffress(
    const float* __restrict__ x,                 // (T,N,2,C)
    ull* __restrict__ simask)                    // (N*C)
{
#pragma clang fp contract(off)
    const int lane = threadIdx.x & 63;
    const int wid  = (blockIdx.x << 2) + (threadIdx.x >> 6);  // n*C + c
    const int n = wid >> 7;
    const int c = wid & 127;

    const float x0 = x[((lane * NN + n) * 2 + 0) * CC + c];
    const float x1 = x[((lane * NN + n) * 2 + 1) * CC + c];
    const ull m0 = __ballot(x0 > 0.5f) << lane;          // bit t = x0[t-lane]
    const ull m1 = __ballot(x1 > 0.5f) << (63 - lane);   // bit t = x1[t-63+lane]

    int ad = lane - (DD / 2);
    if (ad < 0) ad = -ad;
    if (ad == 0) ad = 1;                         // center clamp
    const float kint = 1.0f / (1.0f - expf(-(float)ad * 0.5f));

    const float R = 0.05f;                       // RN(1/20)
    float vj = 0.f;
    unsigned rlo = 0u, rhi = 0u;                 // spike row t (on lane t)

    // t = 0..12: spike provably impossible (max vj = 2(1-0.95^13) < 0.974)
#pragma unroll
    for (int t = 0; t < 13; ++t) {
        const float u = (float)(((unsigned)(m0 >> t) & 1u) +
                                ((unsigned)(m1 >> t) & 1u));
        const float num = u - vj;
        const float q0  = num * R;
        vj = vj + fmaf(fmaf(-20.0f, q0, num), R, q0);
    }

    // t = 13..63: full LIF + ballot capture (rolled)
#pragma clang loop unroll(disable)
    for (int t = 13; t < TT; ++t) {
        const float u = (float)(((unsigned)(m0 >> t) & 1u) +
                                ((unsigned)(m1 >> t) & 1u));
        const float num = u - vj;
        const float q0  = num * R;
        const float q   = fmaf(fmaf(-20.0f, q0, num), R, q0);
        vj = vj + q;

        const bool sp = vj >= 1.0f;
        const ull m = __ballot(sp);
        vj = sp ? 0.0f : vj;
        if (t == lane) { rlo = (unsigned)m; rhi = (unsigned)(m >> 32); }
    }

    // zc[t] on lane t: dot(spike row, kint) — exact (each product is 0 or kd)
    float zc = 0.f;
#pragma clang loop unroll(disable)
    for (int d = 0; d < 64; ++d) {
        const float kd = rdlane(kint, d);
        const unsigned bit = (d < 32) ? ((rlo >> d) & 1u) : ((rhi >> (d - 32)) & 1u);
        zc = fmaf((float)bit, kd, zc);
    }

    // lane-redundant serial integrator IF (zc == 0 for t < 13)
    float vi = 0.f, sreg = 0.f;
#pragma clang loop unroll(disable)
    for (int t = 13; t < TT; ++t) {
        vi += rdlane(zc, t);
        const bool sp = vi >= 1.0f;
        const float siF = sp ? 1.0f : 0.0f;
        vi = sp ? 0.0f : vi;
        if (t == lane) sreg = siF;
    }
    const ull mm = __ballot(sreg > 0.5f);
    if (lane == 0) simask[wid] = mm;
}

// ---------------------------------------------------------------------------
// Kernel B1: square model, 16 lanes per cell (round-4 verbatim).
// 4096 cells, 256 threads/block (16 cells) -> 256 blocks.
// ---------------------------------------------------------------------------
__global__ __launch_bounds__(256) void kB1_square(
    const ull* __restrict__ simask,              // (N*C)
    const float* __restrict__ w1,  const float* __restrict__ b1,
    const float* __restrict__ w2,  const float* __restrict__ b2,
    float* __restrict__ fsbuf)                   // (N*C, T)
{
#pragma clang fp contract(off)
    __shared__ float fsl[16][TT + 1];
    const int tid = threadIdx.x;
    const int g   = tid & 15;                    // lane-in-group = k (0..9 live)
    const int cib = tid >> 4;                    // cell-in-block 0..15
    const int cell = (blockIdx.x << 4) + cib;    // n*C + c

    const ull mm = simask[cell];
    const unsigned mlo = (unsigned)mm, mhi = (unsigned)(mm >> 32);

    const int k = (g < 10) ? g : 0;
    const float W1k = w1[k], B1k = b1[k];
    const float W2k = (g < 10) ? w2[k] : 0.0f;   // dead lanes contribute 0
    const float B2  = b2[0];

    float f1 = 0.f, v1 = 0.f, f2 = 0.f, v2 = 0.f, fs = 0.f;

#pragma unroll
    for (int t = 0; t < TT; ++t) {
        const float si = (float)((t < 32) ? ((mlo >> t) & 1u)
                                          : ((mhi >> (t - 32)) & 1u));
        f1 = f1 * 0.5f + si;

        v1 = v1 + (f1 * W1k + B1k);
        const bool s1b = v1 >= 1.0f;
        const float s1 = s1b ? 1.0f : 0.0f;
        v1 = s1b ? 0.0f : v1;

        f2 = f2 * 0.5f + s1;
        float acc = f2 * W2k;
        acc += __shfl_xor(acc, 1);
        acc += __shfl_xor(acc, 2);
        acc += __shfl_xor(acc, 4);
        acc += __shfl_xor(acc, 8);

        v2 = v2 + (acc + B2);
        const bool s2b = v2 >= 1.0f;
        const float s2 = s2b ? 1.0f : 0.0f;
        v2 = s2b ? 0.0f : v2;

        fs = fs * 0.5f + s2;
        fsl[cib][t] = fs;                        // all 16 lanes, same value
    }
    __syncthreads();

    float* dst = fsbuf + (blockIdx.x << 10);
#pragma unroll
    for (int i = tid; i < 16 * TT; i += 256)
        dst[i] = fsl[i >> 6][i & 63];
}

// ---------------------------------------------------------------------------
// Kernel B2 (lean): one wave per n. Serial chain minimized:
//   - vs-scan precomputed into a uniform 64-bit mask (no per-step readlane)
//   - per-step cross-lane = 2 ballots + 1 shfl_xor only
//   - pv computed locally per half via g2 reconstruction + balanced tree that
//     replicates the old DPP-cascade summation structure exactly; folded in a
//     post-loop pass (off the main chain).
// ---------------------------------------------------------------------------
__global__ __launch_bounds__(64) void kB2_lean(
    const float* __restrict__ fsbuf,             // (N*C, T)
    const float* __restrict__ sw0, const float* __restrict__ sb0,
    const float* __restrict__ sw1, const float* __restrict__ sb1,
    const float* __restrict__ sw2, const float* __restrict__ sb2,
    float* __restrict__ out)                     // (T,N,1)
{
#pragma clang fp contract(off)
    const int n = blockIdx.x;
    const int tid = threadIdx.x;                 // 0..63
    const int k = tid & 31;
    const int h = tid >> 5;
    const int ll = tid & 31;

    // ---- phase 2: lane t sums fs[t] over the 128 cells (round-4 order) ----
    const float* base = fsbuf + n * (CC * TT);
    float a0 = 0.f, a1 = 0.f, a2 = 0.f, a3 = 0.f;
#pragma clang loop unroll(disable)
    for (int c = 0; c < CC; c += 4) {
        a0 += base[(c + 0) * TT + tid];
        a1 += base[(c + 1) * TT + tid];
        a2 += base[(c + 2) * TT + tid];
        a3 += base[(c + 3) * TT + tid];
    }
    const float sums = (a0 + a1) + (a2 + a3);

    // ---- weights ----
    const float SW0 = sw0[k], SB0 = sb0[k], SB1 = sb1[k];
    float SW1[16];
#pragma unroll
    for (int j = 0; j < 16; ++j) SW1[j] = sw1[k * 32 + h * 16 + j];
    float SW2l[16];
#pragma unroll
    for (int j = 0; j < 16; ++j) SW2l[j] = sw2[h * 16 + j];
    const float SB2 = sb2[0];

    // ---- vs pre-scan (uniform on all lanes): spike mask svs ----
    ull svs = 0ull;
    {
        float vsv = 0.f;
#pragma clang loop unroll(disable)
        for (int t = 0; t < TT; ++t) {
            const float p = rdlane(sums, t);
            vsv += p;
            const bool sp = vsv >= 1.0f;
            vsv = sp ? 0.0f : vsv;
            svs |= sp ? (1ull << t) : 0ull;
        }
    }

    // ---- main scan ----
    float q0 = 0.f, q1 = 0.f;
    float g1loc[16], g2loc[16];
#pragma unroll
    for (int j = 0; j < 16; ++j) { g1loc[j] = 0.f; g2loc[j] = 0.f; }
    float Ra = 0.f, Rb = 0.f;

#pragma clang loop unroll(disable)
    for (int t = 0; t < TT; ++t) {
        const float s = (float)((unsigned)(svs >> t) & 1u);

        q0 += s * SW0 + SB0;
        const bool sp0 = q0 >= 1.0f;
        const float s0 = sp0 ? 1.0f : 0.0f;
        q0 *= (1.0f - s0);

        const unsigned m  = (unsigned)__ballot(sp0);
        const unsigned mh = h ? (m >> 16) : m;

        // g1 reconstruction: fma is exact-equivalent (*0.5 is exact)
#pragma unroll
        for (int j = 0; j < 16; ++j)
            g1loc[j] = fmaf(g1loc[j], 0.5f, (float)((mh >> j) & 1u));

        float b0 = 0.f, b1v = 0.f, b2a = 0.f, b3 = 0.f;
#pragma unroll
        for (int j = 0; j < 16; j += 4) {
            b0  += SW1[j + 0] * g1loc[j + 0];
            b1v += SW1[j + 1] * g1loc[j + 1];
            b2a += SW1[j + 2] * g1loc[j + 2];
            b3  += SW1[j + 3] * g1loc[j + 3];
        }
        float part = (b0 + b1v) + (b2a + b3);
        part += __shfl_xor(part, 32);
        q1 += part + SB1;
        const bool sp1 = q1 >= 1.0f;
        const float s1 = sp1 ? 1.0f : 0.0f;
        q1 *= (1.0f - s1);

        const unsigned m2  = (unsigned)__ballot(sp1);
        const unsigned m2h = h ? (m2 >> 16) : m2;

#pragma unroll
        for (int j = 0; j < 16; ++j)
            g2loc[j] = fmaf(g2loc[j], 0.5f, (float)((m2h >> j) & 1u));

        // local products + balanced pair tree (replicates DPP cascade value)
        float p0  = g2loc[0]  * SW2l[0],  p1  = g2loc[1]  * SW2l[1];
        float p2  = g2loc[2]  * SW2l[2],  p3  = g2loc[3]  * SW2l[3];
        float p4  = g2loc[4]  * SW2l[4],  p5  = g2loc[5]  * SW2l[5];
        float p6  = g2loc[6]  * SW2l[6],  p7  = g2loc[7]  * SW2l[7];
        float p8  = g2loc[8]  * SW2l[8],  p9  = g2loc[9]  * SW2l[9];
        float p10 = g2loc[10] * SW2l[10], p11 = g2loc[11] * SW2l[11];
        float p12 = g2loc[12] * SW2l[12], p13 = g2loc[13] * SW2l[13];
        float p14 = g2loc[14] * SW2l[14], p15 = g2loc[15] * SW2l[15];
        const float t0 = (p0 + p1)   + (p2 + p3);
        const float t1 = (p4 + p5)   + (p6 + p7);
        const float t2 = (p8 + p9)   + (p10 + p11);
        const float t3 = (p12 + p13) + (p14 + p15);
        const float Rown = (t0 + t1) + (t2 + t3);

        if (t == ll)      Ra = Rown;             // half-sum R_h at step t
        if (t == ll + 32) Rb = Rown;
    }

    // ---- post-pass: q2 scan + store (off the main chain) ----
    float q2 = 0.f;
#pragma clang loop unroll(disable)
    for (int t = 0; t < TT; ++t) {
        const float r0 = (t < 32) ? rdlane(Ra, t)      : rdlane(Rb, t - 32);
        const float r1 = (t < 32) ? rdlane(Ra, t + 32) : rdlane(Rb, t);
        q2 += (r1 + r0) + SB2;
        if (tid == 0) out[t * NN + n] = q2;
    }
}

// ---------------------------------------------------------------------------
extern "C" void kernel_launch(void* const* d_in, const int* in_sizes, int n_in,
                              void* d_out, int out_size, void* d_ws, size_t ws_size,
                              hipStream_t stream)
{
    const float* x   = (const float*)d_in[0];
    const float* w1  = (const float*)d_in[1];
    const float* b1  = (const float*)d_in[2];
    const float* w2  = (const float*)d_in[3];
    const float* b2  = (const float*)d_in[4];
    const float* sw0 = (const float*)d_in[5];
    const float* sb0 = (const float*)d_in[6];
    const float* sw1 = (const float*)d_in[7];
    const float* sb1 = (const float*)d_in[8];
    const float* sw2 = (const float*)d_in[9];
    const float* sb2 = (const float*)d_in[10];
    float* out = (float*)d_out;

    ull*   simask = (ull*)d_ws;                        // 4096 * 8 B
    float* fsbuf  = (float*)((char*)d_ws + (1 << 20)); // 4096*64*4 B = 1 MiB

    hipLaunchKernelGGL(k1a_jeffress, dim3((NN * CC) / 4), dim3(256), 0, stream,
                       x, simask);
    hipLaunchKernelGGL(kB1_square, dim3((NN * CC) / 16), dim3(256), 0, stream,
                       simask, w1, b1, w2, b2, fsbuf);
    hipLaunchKernelGGL(kB2_lean, dim3(NN), dim3(64), 0, stream,
                       fsbuf, sw0, sb0, sw1, sb1, sw2, sb2, out);
}